// Round 1
// baseline (290.206 us; speedup 1.0000x reference)
//
#include <hip/hip_runtime.h>
#include <hip/hip_bf16.h>

#define T_LEN 4096
#define BATCH 8
#define D_DIM 256
#define P_DIM 256
#define O_DIM 256
#define N3    768

typedef __bf16 bf16;
typedef __attribute__((ext_vector_type(8))) __bf16 bf16x8;
typedef __attribute__((ext_vector_type(4))) __bf16 bf16x4;
typedef __attribute__((ext_vector_type(4))) float f32x4;
typedef __attribute__((ext_vector_type(16))) float f32x16;

#define MFMA16(a, b, c) __builtin_amdgcn_mfma_f32_16x16x32_bf16(a, b, c, 0, 0, 0)
#define MFMA32(a, b, c) __builtin_amdgcn_mfma_f32_32x32x16_bf16(a, b, c, 0, 0, 0)

#define LDS_P 72  // P rows: 144B stride

// lgkm-only barrier: drains LDS (Ps visibility) but leaves global loads in
// flight across the barrier — the compiler's __syncthreads would emit
// s_waitcnt vmcnt(0) and kill the cross-iter prefetch pipeline.
#define BARRIER_LGKM() __asm__ __volatile__("s_waitcnt lgkmcnt(0)\n\ts_barrier" ::: "memory")

// ---------------------------------------------------------------------------
// K0: fragment-major weight pack (proven R6/R7).
// ---------------------------------------------------------------------------
__global__ __launch_bounds__(256) void wpack_kernel(
    const float* __restrict__ src, bf16* __restrict__ dst, int ncols)
{
    const int g = blockIdx.x * 256 + threadIdx.x;
    const int lane = g & 63;
    const int idx = g >> 6;
    const int nt = idx & 3, kt = (idx >> 2) & 7, ch = idx >> 5;
    const int n = ch * 64 + nt * 16 + (lane & 15);
    const int kb = kt * 32 + (lane >> 4) * 8;
    bf16x8 pk;
    #pragma unroll
    for (int j = 0; j < 8; ++j) pk[j] = (bf16)src[(size_t)(kb + j) * ncols + n];
    *(bf16x8*)&dst[(size_t)g * 8] = pk;
}

// ---------------------------------------------------------------------------
// K1 v4: qkv proj -> qb (plain), kpk/vpk (fragment-packed). Proven R7.
// ---------------------------------------------------------------------------
__global__ __launch_bounds__(256) void qkv_proj_kernel(
    const float* __restrict__ query, const bf16* __restrict__ wkp,
    const float* __restrict__ b_kqv,
    bf16* __restrict__ qb, bf16* __restrict__ kpk, bf16* __restrict__ vpk)
{
    __shared__ __align__(16) bf16 Vt[64][68];
    const int m0 = blockIdx.x * 64;
    const int tid = threadIdx.x;
    const int lane = tid & 63, wave = tid >> 6, l15 = lane & 15, quad = lane >> 4;
    const int arow = wave * 16 + l15;

    bf16x8 af[8];
    {
        const float* qsrc = query + (size_t)(m0 + arow) * D_DIM + quad * 8;
        #pragma unroll
        for (int kt = 0; kt < 8; ++kt) {
            float4 f0 = *(const float4*)(qsrc + kt * 32);
            float4 f1 = *(const float4*)(qsrc + kt * 32 + 4);
            af[kt] = bf16x8{(bf16)f0.x, (bf16)f0.y, (bf16)f0.z, (bf16)f0.w,
                            (bf16)f1.x, (bf16)f1.y, (bf16)f1.z, (bf16)f1.w};
        }
    }

    for (int ch = 0; ch < 12; ++ch) {
        f32x4 acc[4];
        #pragma unroll
        for (int i = 0; i < 4; ++i)
            for (int r = 0; r < 4; ++r) acc[i][r] = 0.f;
        #pragma unroll
        for (int kt = 0; kt < 8; ++kt) {
            #pragma unroll
            for (int nt = 0; nt < 4; ++nt) {
                bf16x8 bb = *(const bf16x8*)&wkp[((((size_t)ch * 8 + kt) * 4 + nt) * 64 + lane) * 8];
                acc[nt] = MFMA16(af[kt], bb, acc[nt]);
            }
        }
        if (ch < 4) {
            #pragma unroll
            for (int nt = 0; nt < 4; ++nt) {
                const int c = ch * 64 + nt * 16 + l15;
                const float bias = b_kqv[c];
                #pragma unroll
                for (int r = 0; r < 4; ++r) {
                    const int m = m0 + wave * 16 + quad * 4 + r;
                    const int t = m >> 3, bi = m & 7;
                    qb[((size_t)bi * T_LEN + t) * P_DIM + c] = (bf16)((acc[nt][r] + bias) * 0.0625f);
                }
            }
        } else if (ch < 8) {
            #pragma unroll
            for (int nt = 0; nt < 4; ++nt) {
                const int c = ch * 64 + nt * 16 + l15;
                const float bias = b_kqv[c];
                const int kk = c - 256;
                const int c16 = kk >> 4, halfk = (kk >> 3) & 1, j = kk & 7;
                #pragma unroll
                for (int r = 0; r < 4; ++r) {
                    const int m = m0 + wave * 16 + quad * 4 + r;
                    const int t = m >> 3, bi = m & 7;
                    const int st32 = t >> 5, n31 = t & 31;
                    kpk[((((size_t)bi * 128 + st32) * 16 + c16) * 64 + halfk * 32 + n31) * 8 + j]
                        = (bf16)(acc[nt][r] + bias);
                }
            }
        } else {
            __syncthreads();
            #pragma unroll
            for (int nt = 0; nt < 4; ++nt) {
                const int c = ch * 64 + nt * 16 + l15;
                const float bias = b_kqv[c];
                #pragma unroll
                for (int r = 0; r < 4; ++r)
                    Vt[nt * 16 + l15][wave * 16 + quad * 4 + r] = (bf16)(acc[nt][r] + bias);
            }
            __syncthreads();
            const int t0g = m0 >> 3;
            const int s64 = t0g >> 6, ks = (t0g >> 4) & 3, halfv = (t0g >> 3) & 1;
            #pragma unroll
            for (int uu = 0; uu < 2; ++uu) {
                const int u = tid * 2 + uu;
                const int cl = u >> 3, bi = u & 7;
                bf16x8 pk;
                #pragma unroll
                for (int j = 0; j < 8; ++j) pk[j] = Vt[cl][j * 8 + bi];
                const int cc = (ch - 8) * 64 + cl;
                const int ptG = cc >> 5, n31 = cc & 31;
                *(bf16x8*)&vpk[((((size_t)bi * 64 + s64) * 4 + ks) * 8 + ptG) * 512
                               + (size_t)(halfv * 32 + n31) * 8] = pk;
            }
        }
    }
}

// ---------------------------------------------------------------------------
// K2 v4: flash attention, PV pipelined one iter behind QK.
//  - K-frags: 8 of 16 prefetched one full iter ahead (registers).
//  - V-frags: loaded end of iter i, consumed in PV during iter i+1 (bvA/bvB
//    ping-pong, statically indexed).
//  - PV(i-1) MFMAs emitted in the same region as exp(i) VALU: matrix pipe
//    stays fed during the softmax phase instead of idling behind the barrier.
//  - lgkm-only s_barrier: global loads stay in flight across it.
//  - l row-sums: VALU partials on (float)(bf16)p (bit-exact vs P numerator).
// ---------------------------------------------------------------------------
__global__ __launch_bounds__(256, 2) void flash_attn_kernel(
    const bf16* __restrict__ qb, const bf16* __restrict__ kpk,
    const bf16* __restrict__ vpk, bf16* __restrict__ attn)
{
    __shared__ __align__(16) bf16 Ps[2][64][LDS_P];   // 18.4 KB
    __shared__ float l_red[2][64];                    // [sh][row]

    const int bid = blockIdx.x;
    const int b = bid & 7;                 // bid%8 == XCD: 4 MB KV per XCD L2
    const int t0 = (bid >> 3) * 64;
    const int tid = threadIdx.x;
    const int lane = tid & 63, wave = tid >> 6;
    const int l31 = lane & 31, half = lane >> 5;
    const int rg = wave & 1, sh = wave >> 1;

    // Q A-frags (row=lane&31, k=half*8+j), rows rg*32..+32 — proven layout
    bf16x8 qf[16];
    {
        const bf16* qrow = qb + ((size_t)b * T_LEN + t0 + rg * 32 + l31) * P_DIM + half * 8;
        #pragma unroll
        for (int kt = 0; kt < 16; ++kt) qf[kt] = *(const bf16x8*)(qrow + kt * 16);
    }

    f32x16 acc_o[2][2];   // [t-tile][p-tile]
    float l_part[16];
    #pragma unroll
    for (int i = 0; i < 16; ++i) {
        acc_o[0][0][i] = 0.f; acc_o[0][1][i] = 0.f;
        acc_o[1][0][i] = 0.f; acc_o[1][1][i] = 0.f;
        l_part[i] = 0.f;
    }

    const bf16* kfb = kpk + (size_t)b * 128 * 16 * 512;
    const bf16* vfb = vpk + (size_t)b * 64 * 4 * 8 * 512;

    // prime the K prefetch for s0 = 0
    bf16x8 kpre[8];
    {
        const bf16* kf0 = kfb + ((size_t)sh * 16 * 64 + lane) * 8;
        #pragma unroll
        for (int c = 0; c < 8; ++c) kpre[c] = *(const bf16x8*)(kf0 + (size_t)c * 512);
    }

    bf16x8 bvA[8], bvB[8];   // V-frag ping-pong (load iter i, consume iter i+1)

/* One s0-step. QK for S0; then PV for S0-64 (reads Ps[buf^1] + BVP regs)
   interleaved with exp/Ps[buf] stores; then V-frag loads into BVC for the
   next step; lgkm barrier. All array indices compile-time after unroll.   */
#define FA_ITER(S0, BVP, BVC, DO_PV)                                          \
{                                                                             \
    const int buf = ((S0) >> 6) & 1;                                          \
    const bf16* kf  = kfb + (((size_t)(((S0) >> 5) + sh)) * 16 * 64 + lane) * 8;        \
    const bf16* kfn = kfb + (((size_t)((((S0) + 64) >> 5) + sh)) * 16 * 64 + lane) * 8; \
    bf16x8 kc2[8];                                                            \
    _Pragma("unroll")                                                         \
    for (int c = 0; c < 8; ++c) kc2[c] = *(const bf16x8*)(kf + (size_t)(8 + c) * 512);  \
    f32x16 accs;                                                              \
    _Pragma("unroll")                                                         \
    for (int i = 0; i < 16; ++i) accs[i] = 0.f;                               \
    _Pragma("unroll")                                                         \
    for (int c = 0; c < 8; ++c) accs = MFMA32(qf[c], kpre[c], accs);          \
    _Pragma("unroll")                                                         \
    for (int c = 0; c < 8; ++c) accs = MFMA32(qf[8 + c], kc2[c], accs);       \
    _Pragma("unroll")                                                         \
    for (int c = 0; c < 8; ++c) kpre[c] = *(const bf16x8*)(kfn + (size_t)c * 512);      \
    if (DO_PV) {                                                              \
        const int pbuf = buf ^ 1;                                             \
        _Pragma("unroll")                                                     \
        for (int ks = 0; ks < 4; ++ks) {                                      \
            bf16x8 ap0 = *(const bf16x8*)&Ps[pbuf][l31][ks * 16 + half * 8];  \
            bf16x8 ap1 = *(const bf16x8*)&Ps[pbuf][32 + l31][ks * 16 + half * 8];       \
            acc_o[0][0] = MFMA32(ap0, BVP[ks * 2],     acc_o[0][0]);          \
            acc_o[0][1] = MFMA32(ap0, BVP[ks * 2 + 1], acc_o[0][1]);          \
            acc_o[1][0] = MFMA32(ap1, BVP[ks * 2],     acc_o[1][0]);          \
            acc_o[1][1] = MFMA32(ap1, BVP[ks * 2 + 1], acc_o[1][1]);          \
        }                                                                     \
    }                                                                         \
    _Pragma("unroll")                                                         \
    for (int r = 0; r < 16; ++r) {                                            \
        float p = __expf(accs[r]);                                            \
        bf16 pb = (bf16)p;                                                    \
        l_part[r] += (float)pb;                                               \
        int row = rg * 32 + (r & 3) + 8 * (r >> 2) + 4 * half;                \
        Ps[buf][row][sh * 32 + l31] = pb;                                     \
    }                                                                         \
    const bf16* vf = vfb + (((size_t)((S0) >> 6) * 4) * 8 + wave * 2) * 512 + (size_t)lane * 8; \
    _Pragma("unroll")                                                         \
    for (int ks = 0; ks < 4; ++ks) {                                          \
        BVC[ks * 2]     = *(const bf16x8*)(vf + (size_t)ks * 8 * 512);        \
        BVC[ks * 2 + 1] = *(const bf16x8*)(vf + (size_t)(ks * 8 + 1) * 512);  \
    }                                                                         \
    BARRIER_LGKM();                                                           \
}

    // iter 0 peeled: no PV yet; loads bvA
    FA_ITER(0, bvB, bvA, 0)

    // iters 1..62 as 31 ping-pong pairs
    for (int s0 = 64; s0 < 4032; s0 += 128) {
        FA_ITER(s0,      bvA, bvB, 1)
        FA_ITER(s0 + 64, bvB, bvA, 1)
    }

    // iter 63 (s0 = 4032): PV(62) from bvA, loads bvB
    FA_ITER(4032, bvA, bvB, 1)

    // drain: PV(63) — Ps[1] written iter 63, visible after its barrier
    {
        #pragma unroll
        for (int ks = 0; ks < 4; ++ks) {
            bf16x8 ap0 = *(const bf16x8*)&Ps[1][l31][ks * 16 + half * 8];
            bf16x8 ap1 = *(const bf16x8*)&Ps[1][32 + l31][ks * 16 + half * 8];
            acc_o[0][0] = MFMA32(ap0, bvB[ks * 2],     acc_o[0][0]);
            acc_o[0][1] = MFMA32(ap0, bvB[ks * 2 + 1], acc_o[0][1]);
            acc_o[1][0] = MFMA32(ap1, bvB[ks * 2],     acc_o[1][0]);
            acc_o[1][1] = MFMA32(ap1, bvB[ks * 2 + 1], acc_o[1][1]);
        }
    }
#undef FA_ITER

    // ---- l reduction: across 32 cols (shuffle), then across sh waves (LDS) ----
    #pragma unroll
    for (int r = 0; r < 16; ++r) {
        float v = l_part[r];
        v += __shfl_xor(v, 1, 64);
        v += __shfl_xor(v, 2, 64);
        v += __shfl_xor(v, 4, 64);
        v += __shfl_xor(v, 8, 64);
        v += __shfl_xor(v, 16, 64);
        l_part[r] = v;
    }
    if (l31 == 0) {
        #pragma unroll
        for (int r = 0; r < 16; ++r) {
            const int row = rg * 32 + (r & 3) + 8 * (r >> 2) + 4 * half;
            l_red[sh][row] = l_part[r];
        }
    }
    __syncthreads();

    // epilogue: attn[(t*B+b)*P + p] = O / (l0+l1)
    #pragma unroll
    for (int rt = 0; rt < 2; ++rt) {
        #pragma unroll
        for (int r = 0; r < 16; ++r) {
            const int row = rt * 32 + (r & 3) + 8 * (r >> 2) + 4 * half;
            const float linv = 1.0f / (l_red[0][row] + l_red[1][row]);
            bf16* dst = attn + ((size_t)(t0 + row) * BATCH + b) * P_DIM + wave * 64 + l31;
            dst[0]  = (bf16)(acc_o[rt][0][r] * linv);
            dst[32] = (bf16)(acc_o[rt][1][r] * linv);
        }
    }
}

// ---------------------------------------------------------------------------
// K3 v3: out = attn @ W_out + b_out. LDS-free, packed B-frags (proven).
// ---------------------------------------------------------------------------
__global__ __launch_bounds__(256) void out_proj_kernel(
    const bf16* __restrict__ attn, const bf16* __restrict__ wop,
    const float* __restrict__ b_out, float* __restrict__ out)
{
    const int m0 = blockIdx.x * 64;
    const int tid = threadIdx.x;
    const int lane = tid & 63, wave = tid >> 6, l15 = lane & 15, quad = lane >> 4;
    const int arow = wave * 16 + l15;

    bf16x8 af[8];
    {
        const bf16* asrc = attn + (size_t)(m0 + arow) * P_DIM + quad * 8;
        #pragma unroll
        for (int kt = 0; kt < 8; ++kt) af[kt] = *(const bf16x8*)(asrc + kt * 32);
    }

    for (int ch = 0; ch < 4; ++ch) {
        f32x4 acc[4];
        #pragma unroll
        for (int i = 0; i < 4; ++i)
            for (int r = 0; r < 4; ++r) acc[i][r] = 0.f;
        #pragma unroll
        for (int kt = 0; kt < 8; ++kt) {
            #pragma unroll
            for (int nt = 0; nt < 4; ++nt) {
                bf16x8 bb = *(const bf16x8*)&wop[((((size_t)ch * 8 + kt) * 4 + nt) * 64 + lane) * 8];
                acc[nt] = MFMA16(af[kt], bb, acc[nt]);
            }
        }
        #pragma unroll
        for (int nt = 0; nt < 4; ++nt) {
            const int n = ch * 64 + nt * 16 + l15;
            const float bias = b_out[n];
            #pragma unroll
            for (int r = 0; r < 4; ++r) {
                const int m = m0 + wave * 16 + quad * 4 + r;
                out[(size_t)m * O_DIM + n] = acc[nt][r] + bias;
            }
        }
    }
}

extern "C" void kernel_launch(void* const* d_in, const int* in_sizes, int n_in,
                              void* d_out, int out_size, void* d_ws, size_t ws_size,
                              hipStream_t stream) {
    const float* query = (const float*)d_in[0];
    const float* W_kqv = (const float*)d_in[1];
    const float* b_kqv = (const float*)d_in[2];
    const float* W_out = (const float*)d_in[3];
    const float* b_out = (const float*)d_in[4];
    float* out = (float*)d_out;

    const size_t BUF = (size_t)BATCH * T_LEN * P_DIM;
    bf16* qb   = (bf16*)d_ws;
    bf16* kpk  = qb + BUF;     // fragment-packed K
    bf16* vpk  = kpk + BUF;    // fragment-packed V
    bf16* attn = vpk + BUF;    // [T][B][P]
    bf16* wkp = attn;          // overlay: dead until K2 writes attn
    bf16* wop = qb;            // overlay: packed after K2 consumed qb

    wpack_kernel<<<96, 256, 0, stream>>>(W_kqv, wkp, N3);
    qkv_proj_kernel<<<512, 256, 0, stream>>>(query, wkp, b_kqv, qb, kpk, vpk);
    flash_attn_kernel<<<512, 256, 0, stream>>>(qb, kpk, vpk, attn);
    wpack_kernel<<<32, 256, 0, stream>>>(W_out, wop, O_DIM);
    out_proj_kernel<<<512, 256, 0, stream>>>(attn, wop, b_out, out);
}